// Round 7
// baseline (7027.425 us; speedup 1.0000x reference)
//
#include <hip/hip_runtime.h>
#include <math.h>

// Model: S=1024, V=32000, H=1024. Attention is dead code (softmax over a
// size-1 axis == ones), so context = sum_t enc_out[t].
//
// Round-7 structure: hide all GEMMs under the latency-bound LSTMs via
// sentinel-dataflow fusion (the LSTMs leave ~half the chip idle for 4.3ms).
//
//  K1 enc_phase (grid 640, 512thr):  WG 0..127   encoder LSTM (polls G_enc)
//                                    WG 128..383 G_enc GEMM tiles (WT stores)
//                                    WG 384..639 G_dec partial GEMM tiles
//  ctx_bias_k: ctxb = dec_b + dec_Wih[:,H:] @ ctx
//  K2 dec_phase (grid 2128, 512thr): WG 0..127   decoder LSTM (G_dec+gctx)
//                                    WG 128..    logits tiles, sentinel-poll
//                                                dec_h rows, then plain GEMM
//  argmax_k
//
// Sync primitives (proven rounds 2-6): producers store agent-scope /
// write-through (straight to LLC); consumers poll the DATA for NaN
// sentinels with L2-bypassing loads + s_sleep backoff (hot-spin DDoSes the
// fabric, round 4). Finite LSTM/GEMM outputs can never be NaN.
// Single-scalar progress certificates: decoder WG g storing (t, j) implies
// it polled ALL of h[t-1], so any element of row t+1 certifies rows <= t
// complete. mt=7 tiles poll a shadow completion row written post-loop.
//
// G_dec lives in the d_out tail (floats 28,573,696..32,768,000): logits
// rows r clobber only G_dec rows <= 7.8r-6976 < r, and tile mt starts only
// after decoder step 128mt+127 >= r, so every clobbered row is already
// consumed. mt=7 (the deep tail) starts only after full decoder completion.

#define S_LEN 1024
#define HDIM  1024
#define VDIM  32000
#define GDEC_OFF 28573696   // 32768000 - 4194304

typedef float f4 __attribute__((ext_vector_type(4)));

__device__ __forceinline__ void agent_storef(float* p, float v) {
    __hip_atomic_store(p, v, __ATOMIC_RELAXED, __HIP_MEMORY_SCOPE_AGENT);
}
__device__ __forceinline__ float sigmoidf_(float x) {
    return 1.0f / (1.0f + expf(-x));
}
__device__ __forceinline__ float llc_loadf(const float* p) {
    float v;
    asm volatile("global_load_dword %0, %1, off sc0 sc1\n\t"
                 "s_waitcnt vmcnt(0)"
                 : "=v"(v) : "v"(p) : "memory");
    return v;
}
// 4x16B LLC-coherent loads (bypass L1+L2), single waitcnt.
__device__ __forceinline__ void llc_load_4x4(const float* p, f4& a, f4& b,
                                             f4& c, f4& d) {
    asm volatile(
        "global_load_dwordx4 %0, %4, off sc0 sc1\n\t"
        "global_load_dwordx4 %1, %4, off offset:1024 sc0 sc1\n\t"
        "global_load_dwordx4 %2, %4, off offset:2048 sc0 sc1\n\t"
        "global_load_dwordx4 %3, %4, off offset:3072 sc0 sc1\n\t"
        "s_waitcnt vmcnt(0)"
        : "=&v"(a), "=&v"(b), "=&v"(c), "=&v"(d)
        : "v"(p) : "memory");
}
// Posted 16B write-through store (fire-and-forget; WG end drains vmcnt).
__device__ __forceinline__ void llc_store4(float* p, f4 v) {
    asm volatile("global_store_dwordx4 %0, %1, off sc0 sc1"
                 :: "v"(p), "v"(v) : "memory");
}
__device__ __forceinline__ bool any_nan16(f4 a, f4 b, f4 c, f4 d) {
    float s0 = (a.x + a.y) + (a.z + a.w);
    float s1 = (b.x + b.y) + (b.z + b.w);
    float s2 = (c.x + c.y) + (c.z + c.w);
    float s3 = (d.x + d.y) + (d.z + d.w);
    float s  = (s0 + s1) + (s2 + s3);
    return s != s;
}
// LDS f4-slot swizzle: uniform 8-words/bank for writer/reader patterns.
__device__ __forceinline__ int swz(int s) {
    return (s & ~7) | ((s ^ (s >> 3)) & 7);
}

// ---------------------------------------------------------------------------
// Persistent sequential LSTM block (round-5 proven body). 512 threads.
// GMODE 0: encoder — gate preactivations polled from G (NaN sentinel, bypass)
// GMODE 1: decoder — plain G loads + per-thread gctx; writes shadow row slen.
// ---------------------------------------------------------------------------
template<int GMODE>
__device__ void lstm_block(const float* __restrict__ Whh,
                           const float* __restrict__ G,
                           const float* __restrict__ gctx_vec,
                           const float* __restrict__ h_init,
                           const float* __restrict__ c_init,
                           float* __restrict__ h_out,
                           float* __restrict__ c_fin,
                           float* __restrict__ csum_out,
                           int slen)
{
    __builtin_amdgcn_s_setprio(1);     // defend vs co-resident GEMM waves
    __shared__ f4 hbuf[256];
    const int tid = threadIdx.x;
    const int g   = blockIdx.x;
    const int wv  = tid >> 6;
    const int lg  = tid & 63;
    const int j   = g * 8 + wv;

    f4 W[4][4];
#pragma unroll
    for (int q = 0; q < 4; ++q)
#pragma unroll
        for (int i = 0; i < 4; ++i)
            W[q][i] = *(const f4*)(Whh + (size_t)(j + q * HDIM) * HDIM
                                   + 4 * lg + 256 * i);

    float c = 0.0f, csum = 0.0f;
    if (lg == 0) c = c_init[j];

    float gctx = 0.0f;
    if (GMODE == 1) gctx = gctx_vec[(size_t)(lg & 3) * HDIM + j];

    float gnow;
    {
        const float* gp = G + (size_t)(lg & 3) * HDIM + j;
        if (GMODE == 0) {
            gnow = llc_loadf(gp);
            while (__any(gnow != gnow)) {
                if (gnow != gnow) { __builtin_amdgcn_s_sleep(2); gnow = llc_loadf(gp); }
            }
        } else {
            gnow = *gp + gctx;
        }
    }

    for (int t = 0; t < slen; ++t) {
#pragma unroll
        for (int q = 0; q < 4; ++q)
#pragma unroll
            for (int i = 0; i < 4; ++i)
                asm volatile("" : "+v"(W[q][i]));

        const float* hp = (t == 0) ? h_init : (h_out + (size_t)(t - 1) * HDIM);

        if (wv == 0) {
            f4 a, b, cc, d;
            const float* p = hp + 4 * lg;
            for (;;) {
                llc_load_4x4(p, a, b, cc, d);
                if (!__any(any_nan16(a, b, cc, d))) break;
                __builtin_amdgcn_s_sleep(1);
            }
            hbuf[swz(lg)]       = a;
            hbuf[swz(64 + lg)]  = b;
            hbuf[swz(128 + lg)] = cc;
            hbuf[swz(192 + lg)] = d;
        }
        __syncthreads();

        // next step's G value (consumed next iteration)
        int tn = (t + 1 < slen) ? (t + 1) : t;
        const float* gp = G + (size_t)tn * (4 * HDIM) + (lg & 3) * HDIM + j;
        float gnext;
        if (GMODE == 0) {
            gnext = llc_loadf(gp);
            while (__any(gnext != gnext)) {
                if (gnext != gnext) { __builtin_amdgcn_s_sleep(2); gnext = llc_loadf(gp); }
            }
        } else {
            gnext = *gp + gctx;
        }

        f4 h0 = hbuf[swz(lg)];
        f4 h1 = hbuf[swz(64 + lg)];
        f4 h2 = hbuf[swz(128 + lg)];
        f4 h3 = hbuf[swz(192 + lg)];
        float p0 = 0.f, p1 = 0.f, p2 = 0.f, p3 = 0.f;
        f4 hv;
#pragma unroll
        for (int i = 0; i < 4; ++i) {
            hv = (i == 0) ? h0 : (i == 1) ? h1 : (i == 2) ? h2 : h3;
            p0 = fmaf(W[0][i].x, hv.x, fmaf(W[0][i].y, hv.y,
                 fmaf(W[0][i].z, hv.z, fmaf(W[0][i].w, hv.w, p0))));
            p1 = fmaf(W[1][i].x, hv.x, fmaf(W[1][i].y, hv.y,
                 fmaf(W[1][i].z, hv.z, fmaf(W[1][i].w, hv.w, p1))));
            p2 = fmaf(W[2][i].x, hv.x, fmaf(W[2][i].y, hv.y,
                 fmaf(W[2][i].z, hv.z, fmaf(W[2][i].w, hv.w, p2))));
            p3 = fmaf(W[3][i].x, hv.x, fmaf(W[3][i].y, hv.y,
                 fmaf(W[3][i].z, hv.z, fmaf(W[3][i].w, hv.w, p3))));
        }

        float t01 = __shfl_xor((lg & 1) ? p0 : p1, 1);
        float s01 = ((lg & 1) ? p1 : p0) + t01;
        float t23 = __shfl_xor((lg & 1) ? p2 : p3, 1);
        float s23 = ((lg & 1) ? p3 : p2) + t23;
        float tq  = __shfl_xor((lg & 2) ? s01 : s23, 2);
        float s   = ((lg & 2) ? s23 : s01) + tq;
        s += __shfl_xor(s, 4);
        s += __shfl_xor(s, 8);
        s += __shfl_xor(s, 16);
        s += __shfl_xor(s, 32);

        float pre = s + gnow;
        float act = ((lg & 3) == 2) ? tanhf(pre) : sigmoidf_(pre);
        float a1 = __shfl(act, 1);
        float a2 = __shfl(act, 2);
        float a3 = __shfl(act, 3);

        if (lg == 0) {
            c = a1 * c + act * a2;
            float h = a3 * tanhf(c);
            csum += h;
            agent_storef(h_out + (size_t)t * HDIM + j, h);
        }
        gnow = gnext;

        __syncthreads();
    }

    if (lg == 0) {
        if (c_fin)    c_fin[j]    = c;
        if (csum_out) csum_out[j] = csum;
        if (GMODE == 1)   // shadow completion row for logits mt=7 pollers
            agent_storef(h_out + (size_t)slen * HDIM + j, 0.0f);
    }
}

// ---------------------------------------------------------------------------
// 512-thread 128x128 GEMM tile: C = A_eff(128,K) @ B(128,K)^T + bias.
// MODE 0: logits — sentinel pre-poll on pollbuf(dec_h), plain loads/stores
// MODE 1: G_enc — A = embed[gidx[m]], write-through C stores (polled live)
// MODE 2: G_dec — A = relu(embed[gidx[m-1]]), row0 = 0, no bias, plain C
// ---------------------------------------------------------------------------
template<int MODE>
__device__ void gemm_tile(const float* __restrict__ A, int lda,
                          const float* __restrict__ B, int ldb,
                          const float* __restrict__ bias,
                          float* __restrict__ C, int ldc,
                          const float* __restrict__ embed,
                          const int* __restrict__ gidx,
                          int mt, int nt, int K,
                          const float* __restrict__ pollbuf)
{
    __shared__ float As[16][128];
    __shared__ float Bs[16][128];
    const int tid = threadIdx.x;
    const int m0 = mt * 128;
    const int n0 = nt * 128;

    if (MODE == 0) {
        // progress certificate: any element of row m0+128 implies rows
        // <= m0+127 complete; mt=7 polls the full shadow row (=1024).
        if (mt < 7) {
            if (tid == 0) {
                const float* p = pollbuf + (size_t)(m0 + 128) * HDIM;
                float v = llc_loadf(p);
                while (v != v) { __builtin_amdgcn_s_sleep(16); v = llc_loadf(p); }
            }
        } else {
            if (tid < 64) {
                const float* p = pollbuf + (size_t)S_LEN * HDIM + 4 * tid;
                f4 a, b, cc, d;
                for (;;) {
                    llc_load_4x4(p, a, b, cc, d);
                    if (!__any(any_nan16(a, b, cc, d))) break;
                    __builtin_amdgcn_s_sleep(16);
                }
            }
        }
        __syncthreads();
    }

    float acc[8][4];
#pragma unroll
    for (int r = 0; r < 8; ++r)
#pragma unroll
        for (int cc = 0; cc < 4; ++cc) acc[r][cc] = 0.0f;

    const int ty = tid >> 5;    // 0..15
    const int tx = tid & 31;    // 0..31
    const int lm = tid >> 2;    // 0..127 load row
    const int c4 = (tid & 3) * 4;

    for (int k0 = 0; k0 < K; k0 += 16) {
        float4 v;
        if (MODE == 0) {
            v = *(const float4*)(A + (size_t)(m0 + lm) * lda + k0 + c4);
        } else if (MODE == 1) {
            int row = gidx[m0 + lm];
            v = *(const float4*)(embed + (size_t)row * HDIM + k0 + c4);
        } else {
            int mg = m0 + lm;
            if (mg == 0) {
                v = make_float4(0.f, 0.f, 0.f, 0.f);
            } else {
                int row = gidx[mg - 1];
                v = *(const float4*)(embed + (size_t)row * HDIM + k0 + c4);
                v.x = fmaxf(v.x, 0.f); v.y = fmaxf(v.y, 0.f);
                v.z = fmaxf(v.z, 0.f); v.w = fmaxf(v.w, 0.f);
            }
        }
        As[c4 + 0][lm] = v.x; As[c4 + 1][lm] = v.y;
        As[c4 + 2][lm] = v.z; As[c4 + 3][lm] = v.w;

        float4 w = *(const float4*)(B + (size_t)(n0 + lm) * ldb + k0 + c4);
        Bs[c4 + 0][lm] = w.x; Bs[c4 + 1][lm] = w.y;
        Bs[c4 + 2][lm] = w.z; Bs[c4 + 3][lm] = w.w;
        __syncthreads();

#pragma unroll
        for (int k = 0; k < 16; ++k) {
            f4 a0 = *(const f4*)&As[k][ty * 8];
            f4 a1 = *(const f4*)&As[k][ty * 8 + 4];
            f4 b  = *(const f4*)&Bs[k][tx * 4];
            float av[8] = {a0.x,a0.y,a0.z,a0.w,a1.x,a1.y,a1.z,a1.w};
            float bv[4] = {b.x,b.y,b.z,b.w};
#pragma unroll
            for (int r = 0; r < 8; ++r)
#pragma unroll
                for (int cc = 0; cc < 4; ++cc)
                    acc[r][cc] = fmaf(av[r], bv[cc], acc[r][cc]);
        }
        __syncthreads();
    }

    const int mbase = m0 + ty * 8;
    const int nbase = n0 + tx * 4;
#pragma unroll
    for (int r = 0; r < 8; ++r) {
        f4 o;
        o.x = acc[r][0] + ((MODE == 2) ? 0.f : bias[nbase + 0]);
        o.y = acc[r][1] + ((MODE == 2) ? 0.f : bias[nbase + 1]);
        o.z = acc[r][2] + ((MODE == 2) ? 0.f : bias[nbase + 2]);
        o.w = acc[r][3] + ((MODE == 2) ? 0.f : bias[nbase + 3]);
        float* cp = C + (size_t)(mbase + r) * ldc + nbase;
        if (MODE == 1) llc_store4(cp, o);     // pollers read via LLC
        else           *(f4*)cp = o;          // plain (kernel-boundary flush)
    }
}

// ---------------------------------------------------------------------------
__global__ __launch_bounds__(512, 1)
void enc_phase(const float* __restrict__ embed,
               const int* __restrict__ input_seq,
               const int* __restrict__ gold_seq,
               const float* __restrict__ enc_Wih,
               const float* __restrict__ enc_b,
               const float* __restrict__ dec_Wih,
               const float* __restrict__ enc_Whh,
               float* __restrict__ G_enc,
               float* __restrict__ G_dec,
               const float* __restrict__ zerovec,
               float* __restrict__ enc_out,
               float* __restrict__ c0,
               float* __restrict__ ctx)
{
    const int bid = blockIdx.x;
    if (bid < 128) {
        lstm_block<0>(enc_Whh, G_enc, nullptr, zerovec, zerovec,
                      enc_out, c0, ctx, S_LEN);
    } else if (bid < 384) {
        int q = bid - 128;
        gemm_tile<1>(nullptr, 0, enc_Wih, HDIM, enc_b, G_enc, 4 * HDIM,
                     embed, input_seq, q >> 5, q & 31, HDIM, nullptr);
    } else {
        int q = bid - 384;
        gemm_tile<2>(nullptr, 0, dec_Wih, 2 * HDIM, nullptr, G_dec, 4 * HDIM,
                     embed, gold_seq, q >> 5, q & 31, HDIM, nullptr);
    }
}

__global__ __launch_bounds__(512, 1)
void dec_phase(const float* __restrict__ dec_Whh,
               const float* __restrict__ G_dec,
               const float* __restrict__ ctxb,
               const float* __restrict__ h_init,
               const float* __restrict__ c0,
               float* __restrict__ dec_h,
               const float* __restrict__ out_w,
               const float* __restrict__ out_b,
               float* __restrict__ out)
{
    const int bid = blockIdx.x;
    if (bid < 128) {
        lstm_block<1>(dec_Whh, G_dec, ctxb, h_init, c0,
                      dec_h, nullptr, nullptr, S_LEN);
    } else {
        int q = bid - 128;
        int mt = q / 250;
        int nt = q % 250;
        gemm_tile<0>(dec_h, HDIM, out_w, HDIM, out_b, out, VDIM,
                     nullptr, nullptr, mt, nt, HDIM, dec_h);
    }
}

// ctx_bias[r] = dec_b[r] + dot(dec_Wih[r, H:2H], context)
__global__ __launch_bounds__(256)
void ctx_bias_k(const float* __restrict__ dec_Wih,
                const float* __restrict__ dec_b,
                const float* __restrict__ ctx,
                float* __restrict__ out)
{
    const int wv = threadIdx.x >> 6;
    const int lane = threadIdx.x & 63;
    const int r = blockIdx.x * 4 + wv;
    const float* wr = dec_Wih + (size_t)r * (2 * HDIM) + HDIM;
    float s = 0.f;
    for (int k = lane; k < HDIM; k += 64) s += wr[k] * ctx[k];
#pragma unroll
    for (int off = 32; off > 0; off >>= 1) s += __shfl_xor(s, off);
    if (lane == 0) out[r] = s + dec_b[r];
}

// per-row argmax (numpy tie rule: first index)
__global__ __launch_bounds__(256)
void argmax_k(const float* __restrict__ logits, float* __restrict__ out_idx)
{
    __shared__ float bv[256];
    __shared__ int   bidx[256];
    const int row = blockIdx.x;
    const int tid = threadIdx.x;
    const float* p = logits + (size_t)row * VDIM;
    float best = -INFINITY;
    int   bi   = 0;
    for (int v = tid; v < VDIM; v += 256) {
        float x = p[v];
        if (x > best) { best = x; bi = v; }
    }
    bv[tid] = best; bidx[tid] = bi;
    __syncthreads();
    for (int s = 128; s > 0; s >>= 1) {
        if (tid < s) {
            if (bv[tid + s] > bv[tid] ||
                (bv[tid + s] == bv[tid] && bidx[tid + s] < bidx[tid])) {
                bv[tid] = bv[tid + s];
                bidx[tid] = bidx[tid + s];
            }
        }
        __syncthreads();
    }
    if (tid == 0) out_idx[row] = (float)bidx[0];
}

extern "C" void kernel_launch(void* const* d_in, const int* in_sizes, int n_in,
                              void* d_out, int out_size, void* d_ws, size_t ws_size,
                              hipStream_t stream)
{
    (void)in_sizes; (void)n_in; (void)out_size; (void)ws_size;

    const int*   input_seq = (const int*)d_in[0];
    const int*   gold_seq  = (const int*)d_in[1];
    const float* embed     = (const float*)d_in[2];
    const float* enc_Wih   = (const float*)d_in[3];
    const float* enc_Whh   = (const float*)d_in[4];
    const float* enc_b     = (const float*)d_in[5];
    const float* dec_Wih   = (const float*)d_in[6];
    const float* dec_Whh   = (const float*)d_in[7];
    const float* dec_b     = (const float*)d_in[8];
    // d_in[9..14]: attention params — dead code
    const float* out_w     = (const float*)d_in[15];
    const float* out_b     = (const float*)d_in[16];

    float* out = (float*)d_out;

    // d_out scratch: G_enc at head (dead before logits rows 0..131 written);
    // G_dec in the tail (clobber-ordering proof in header comment).
    float* G_enc = out;                   // 4,194,304 floats
    float* G_dec = out + GDEC_OFF;        // 4,194,304 floats, ends at 32,768,000

    // workspace
    float* zerovec = (float*)d_ws + 256;        // 1024
    float* c0      = zerovec + 1024;            // 1024
    float* ctx     = c0 + 1024;                 // 1024
    float* ctxb    = ctx + 1024;                // 4096
    float* enc_out = ctxb + 4096;               // S*H
    float* dec_h   = enc_out + 1048576;         // (S+1)*H  (shadow row)

    hipMemsetAsync(d_ws, 0, 5120, stream);                       // zerovec
    hipMemsetAsync(enc_out, 0xFF, (size_t)S_LEN * HDIM * 4, stream);
    hipMemsetAsync(dec_h,   0xFF, (size_t)(S_LEN + 1) * HDIM * 4, stream);
    hipMemsetAsync(G_enc,   0xFF, (size_t)S_LEN * 4 * HDIM * 4, stream);

    // K1: encoder LSTM + G_enc GEMM + G_dec partial GEMM (fused dataflow)
    enc_phase<<<640, 512, 0, stream>>>(
        embed, input_seq, gold_seq, enc_Wih, enc_b, dec_Wih, enc_Whh,
        G_enc, G_dec, zerovec, enc_out, c0, ctx);

    // ctxb = dec_b + dec_Wih[:,H:] @ ctx
    ctx_bias_k<<<1024, 256, 0, stream>>>(dec_Wih, dec_b, ctx, ctxb);

    // K2: decoder LSTM + logits GEMM (sentinel-consumer) fused
    dec_phase<<<2128, 512, 0, stream>>>(
        dec_Whh, G_dec, ctxb, enc_out + (size_t)(S_LEN - 1) * HDIM, c0,
        dec_h, out_w, out_b, out);

    // idxs -> d_out[S*V : S*V + S)
    argmax_k<<<1024, 256, 0, stream>>>(out, out + (size_t)S_LEN * VDIM);
}

// Round 8
// 5651.751 us; speedup vs baseline: 1.2434x; 1.2434x over previous
//
#include <hip/hip_runtime.h>
#include <math.h>

// Model: S=1024, V=32000, H=1024. Attention dead code => context = sum enc_h.
//
// Round-8 structure:
//   memsets (ws ctrl+zerovec zero; enc_out/dec_h NaN sentinel)
//   g_both   : G_enc and G_dec GEMMs in ONE launch (grid 32x16, 256thr)
//   lstm_seq : encoder, round-5 proven (128 WG x 512thr, sentinel poll)
//   ctx_bias : ctxb = dec_b + dec_Wih[:,H:] @ ctx
//   dec_fused: 128 decoder-LSTM WGs (CU-registered) + 2000 logits worker WGs.
//              Workers: sleep ~7us -> exit if on an LSTM CU (cuslot bitmap,
//              HW_ID|XCC_ID key) -> else pull tiles from an atomic TICKET
//              queue; per tile: progress-certificate poll on dec_h, plain
//              GEMM, fused argmax (u64 atomicMax). After the recurrence the
//              LSTM WGs JOIN the ticket queue (deadlock-proof safety net).
//   idx_final: decode argmax keys -> d_out[S*V..]
//
// Certificates (proven round 7): decoder WG at step T polled ALL of row T-1,
// so one scalar of row m0+128 certifies rows <= m0+127 visible in LLC; the
// shadow row (slen) certifies full completion (polled in full for mt=7).
// G_dec lives in the d_out tail: logits row r clobbers only G_dec rows
// <= 7.81r-6976, all consumed before the writing tile's certificate passes.

#define S_LEN 1024
#define HDIM  1024
#define VDIM  32000
#define GDEC_OFF 28573696   // 32768000 - 4194304
#define NTILE_M 8
#define NTILE_N 250
#define NTICKETS (NTILE_M * NTILE_N)

typedef float f4 __attribute__((ext_vector_type(4)));

__device__ __forceinline__ void agent_storef(float* p, float v) {
    __hip_atomic_store(p, v, __ATOMIC_RELAXED, __HIP_MEMORY_SCOPE_AGENT);
}
__device__ __forceinline__ void agent_storei(int* p, int v) {
    __hip_atomic_store(p, v, __ATOMIC_RELAXED, __HIP_MEMORY_SCOPE_AGENT);
}
__device__ __forceinline__ float sigmoidf_(float x) {
    return 1.0f / (1.0f + expf(-x));
}
__device__ __forceinline__ float llc_loadf(const float* p) {
    float v;
    asm volatile("global_load_dword %0, %1, off sc0 sc1\n\t"
                 "s_waitcnt vmcnt(0)"
                 : "=v"(v) : "v"(p) : "memory");
    return v;
}
__device__ __forceinline__ int llc_loadi(const int* p) {
    int v;
    asm volatile("global_load_dword %0, %1, off sc0 sc1\n\t"
                 "s_waitcnt vmcnt(0)"
                 : "=v"(v) : "v"(p) : "memory");
    return v;
}
__device__ __forceinline__ void llc_load_4x4(const float* p, f4& a, f4& b,
                                             f4& c, f4& d) {
    asm volatile(
        "global_load_dwordx4 %0, %4, off sc0 sc1\n\t"
        "global_load_dwordx4 %1, %4, off offset:1024 sc0 sc1\n\t"
        "global_load_dwordx4 %2, %4, off offset:2048 sc0 sc1\n\t"
        "global_load_dwordx4 %3, %4, off offset:3072 sc0 sc1\n\t"
        "s_waitcnt vmcnt(0)"
        : "=&v"(a), "=&v"(b), "=&v"(c), "=&v"(d)
        : "v"(p) : "memory");
}
__device__ __forceinline__ bool any_nan16(f4 a, f4 b, f4 c, f4 d) {
    float s0 = (a.x + a.y) + (a.z + a.w);
    float s1 = (b.x + b.y) + (b.z + b.w);
    float s2 = (c.x + c.y) + (c.z + c.w);
    float s3 = (d.x + d.y) + (d.z + d.w);
    float s  = (s0 + s1) + (s2 + s3);
    return s != s;
}
__device__ __forceinline__ int swz(int s) {
    return (s & ~7) | ((s ^ (s >> 3)) & 7);
}
// Unique-per-CU key from HW_ID bits [15:8] (CU/SH/SE, excludes wave/simd and
// TG bits) + XCC_ID. Wrong decoding degrades gracefully (perf only).
__device__ __forceinline__ int cu_key() {
    unsigned hwid = __builtin_amdgcn_s_getreg((31 << 11) | (0 << 6) | 4);
    unsigned xcc  = __builtin_amdgcn_s_getreg((31 << 11) | (0 << 6) | 20);
    return (int)(((hwid >> 8) & 0xFF) | ((xcc & 7) << 8));   // [0,2048)
}

// ---------------------------------------------------------------------------
// Round-5 proven 256-thread 128x128 GEMM tile body (input GEMMs).
// MODE 1: A = embed[gidx[m]], bias; MODE 2: A = relu(embed[gidx[m-1]]), row0=0
// ---------------------------------------------------------------------------
template<int MODE>
__device__ void gemm_body(const float* __restrict__ B, int ldb,
                          const float* __restrict__ bias,
                          float* __restrict__ C, int ldc,
                          const float* __restrict__ embed,
                          const int* __restrict__ gidx,
                          int m0, int n0, int K)
{
    __shared__ float As[16][128];
    __shared__ float Bs[16][128];
    const int tid = threadIdx.x;

    float acc[8][8];
#pragma unroll
    for (int r = 0; r < 8; ++r)
#pragma unroll
        for (int c = 0; c < 8; ++c) acc[r][c] = 0.0f;

    const int ty = tid >> 4;
    const int tx = tid & 15;

    for (int k0 = 0; k0 < K; k0 += 16) {
#pragma unroll
        for (int q = 0; q < 2; ++q) {
            int id = tid * 2 + q;
            int m  = id >> 2;
            int c4 = (id & 3) * 4;
            float4 v;
            if (MODE == 1) {
                int row = gidx[m0 + m];
                v = *(const float4*)(embed + (size_t)row * HDIM + k0 + c4);
            } else {
                int mg = m0 + m;
                if (mg == 0) {
                    v = make_float4(0.f, 0.f, 0.f, 0.f);
                } else {
                    int row = gidx[mg - 1];
                    v = *(const float4*)(embed + (size_t)row * HDIM + k0 + c4);
                    v.x = fmaxf(v.x, 0.f); v.y = fmaxf(v.y, 0.f);
                    v.z = fmaxf(v.z, 0.f); v.w = fmaxf(v.w, 0.f);
                }
            }
            As[c4 + 0][m] = v.x; As[c4 + 1][m] = v.y;
            As[c4 + 2][m] = v.z; As[c4 + 3][m] = v.w;
        }
#pragma unroll
        for (int q = 0; q < 2; ++q) {
            int id = tid * 2 + q;
            int n  = id >> 2;
            int c4 = (id & 3) * 4;
            float4 v = *(const float4*)(B + (size_t)(n0 + n) * ldb + k0 + c4);
            Bs[c4 + 0][n] = v.x; Bs[c4 + 1][n] = v.y;
            Bs[c4 + 2][n] = v.z; Bs[c4 + 3][n] = v.w;
        }
        __syncthreads();
#pragma unroll
        for (int k = 0; k < 16; ++k) {
            float4 a0 = *(const float4*)&As[k][ty * 8];
            float4 a1 = *(const float4*)&As[k][ty * 8 + 4];
            float4 b0 = *(const float4*)&Bs[k][tx * 8];
            float4 b1 = *(const float4*)&Bs[k][tx * 8 + 4];
            float av[8] = {a0.x,a0.y,a0.z,a0.w,a1.x,a1.y,a1.z,a1.w};
            float bv[8] = {b0.x,b0.y,b0.z,b0.w,b1.x,b1.y,b1.z,b1.w};
#pragma unroll
            for (int r = 0; r < 8; ++r)
#pragma unroll
                for (int c = 0; c < 8; ++c)
                    acc[r][c] = fmaf(av[r], bv[c], acc[r][c]);
        }
        __syncthreads();
    }

    const int mbase = m0 + ty * 8;
    const int nbase = n0 + tx * 8;
#pragma unroll
    for (int r = 0; r < 8; ++r) {
        float4 o0, o1;
        float b0 = (MODE == 2) ? 0.f : bias[nbase + 0];
        float b1 = (MODE == 2) ? 0.f : bias[nbase + 1];
        float b2 = (MODE == 2) ? 0.f : bias[nbase + 2];
        float b3 = (MODE == 2) ? 0.f : bias[nbase + 3];
        float b4 = (MODE == 2) ? 0.f : bias[nbase + 4];
        float b5 = (MODE == 2) ? 0.f : bias[nbase + 5];
        float b6 = (MODE == 2) ? 0.f : bias[nbase + 6];
        float b7 = (MODE == 2) ? 0.f : bias[nbase + 7];
        o0.x = acc[r][0] + b0; o0.y = acc[r][1] + b1;
        o0.z = acc[r][2] + b2; o0.w = acc[r][3] + b3;
        o1.x = acc[r][4] + b4; o1.y = acc[r][5] + b5;
        o1.z = acc[r][6] + b6; o1.w = acc[r][7] + b7;
        *(float4*)(C + (size_t)(mbase + r) * ldc + nbase)     = o0;
        *(float4*)(C + (size_t)(mbase + r) * ldc + nbase + 4) = o1;
    }
}

// Both input GEMMs in one launch: by<8 -> G_enc tile, else G_dec tile.
__global__ __launch_bounds__(256)
void g_both(const float* __restrict__ embed,
            const int* __restrict__ input_seq,
            const int* __restrict__ gold_seq,
            const float* __restrict__ enc_Wih,
            const float* __restrict__ enc_b,
            const float* __restrict__ dec_Wih,
            float* __restrict__ G_enc,
            float* __restrict__ G_dec)
{
    const int bx = blockIdx.x, by = blockIdx.y;
    if (by < 8)
        gemm_body<1>(enc_Wih, HDIM, enc_b, G_enc, 4 * HDIM,
                     embed, input_seq, by * 128, bx * 128, HDIM);
    else
        gemm_body<2>(dec_Wih, 2 * HDIM, nullptr, G_dec, 4 * HDIM,
                     embed, gold_seq, (by - 8) * 128, bx * 128, HDIM);
}

// ---------------------------------------------------------------------------
// Encoder LSTM — round-5 proven kernel, verbatim.
// ---------------------------------------------------------------------------
__global__ __launch_bounds__(512, 2)
void lstm_seq(const float* __restrict__ Whh,
              const float* __restrict__ G,
              const float* __restrict__ h_init,
              const float* __restrict__ c_init,
              float* __restrict__ h_out,
              float* __restrict__ c_fin,
              float* __restrict__ csum_out,
              int slen)
{
    __shared__ f4 hbuf[256];
    const int tid = threadIdx.x;
    const int g   = blockIdx.x;
    const int wv  = tid >> 6;
    const int lg  = tid & 63;
    const int j   = g * 8 + wv;

    f4 W[4][4];
#pragma unroll
    for (int q = 0; q < 4; ++q)
#pragma unroll
        for (int i = 0; i < 4; ++i)
            W[q][i] = *(const f4*)(Whh + (size_t)(j + q * HDIM) * HDIM
                                   + 4 * lg + 256 * i);

    float c = 0.0f, csum = 0.0f;
    if (lg == 0) c = c_init[j];

    float gnow = G[(size_t)(lg & 3) * HDIM + j];

    for (int t = 0; t < slen; ++t) {
#pragma unroll
        for (int q = 0; q < 4; ++q)
#pragma unroll
            for (int i = 0; i < 4; ++i)
                asm volatile("" : "+v"(W[q][i]));

        const float* hp = (t == 0) ? h_init : (h_out + (size_t)(t - 1) * HDIM);

        if (wv == 0) {
            f4 a, b, cc, d;
            const float* p = hp + 4 * lg;
            for (;;) {
                llc_load_4x4(p, a, b, cc, d);
                if (!__any(any_nan16(a, b, cc, d))) break;
                __builtin_amdgcn_s_sleep(1);
            }
            hbuf[swz(lg)]       = a;
            hbuf[swz(64 + lg)]  = b;
            hbuf[swz(128 + lg)] = cc;
            hbuf[swz(192 + lg)] = d;
        }
        __syncthreads();

        int tn = (t + 1 < slen) ? (t + 1) : t;
        float gnext = G[(size_t)tn * (4 * HDIM) + (lg & 3) * HDIM + j];

        f4 h0 = hbuf[swz(lg)];
        f4 h1 = hbuf[swz(64 + lg)];
        f4 h2 = hbuf[swz(128 + lg)];
        f4 h3 = hbuf[swz(192 + lg)];
        float p0 = 0.f, p1 = 0.f, p2 = 0.f, p3 = 0.f;
        f4 hv;
#pragma unroll
        for (int i = 0; i < 4; ++i) {
            hv = (i == 0) ? h0 : (i == 1) ? h1 : (i == 2) ? h2 : h3;
            p0 = fmaf(W[0][i].x, hv.x, fmaf(W[0][i].y, hv.y,
                 fmaf(W[0][i].z, hv.z, fmaf(W[0][i].w, hv.w, p0))));
            p1 = fmaf(W[1][i].x, hv.x, fmaf(W[1][i].y, hv.y,
                 fmaf(W[1][i].z, hv.z, fmaf(W[1][i].w, hv.w, p1))));
            p2 = fmaf(W[2][i].x, hv.x, fmaf(W[2][i].y, hv.y,
                 fmaf(W[2][i].z, hv.z, fmaf(W[2][i].w, hv.w, p2))));
            p3 = fmaf(W[3][i].x, hv.x, fmaf(W[3][i].y, hv.y,
                 fmaf(W[3][i].z, hv.z, fmaf(W[3][i].w, hv.w, p3))));
        }

        float t01 = __shfl_xor((lg & 1) ? p0 : p1, 1);
        float s01 = ((lg & 1) ? p1 : p0) + t01;
        float t23 = __shfl_xor((lg & 1) ? p2 : p3, 1);
        float s23 = ((lg & 1) ? p3 : p2) + t23;
        float tq  = __shfl_xor((lg & 2) ? s01 : s23, 2);
        float s   = ((lg & 2) ? s23 : s01) + tq;
        s += __shfl_xor(s, 4);
        s += __shfl_xor(s, 8);
        s += __shfl_xor(s, 16);
        s += __shfl_xor(s, 32);

        float pre = s + gnow;
        float act = ((lg & 3) == 2) ? tanhf(pre) : sigmoidf_(pre);
        float a1 = __shfl(act, 1);
        float a2 = __shfl(act, 2);
        float a3 = __shfl(act, 3);

        if (lg == 0) {
            c = a1 * c + act * a2;
            float h = a3 * tanhf(c);
            csum += h;
            agent_storef(h_out + (size_t)t * HDIM + j, h);
        }
        gnow = gnext;
        __syncthreads();
    }

    if (lg == 0) {
        if (c_fin)    c_fin[j]    = c;
        if (csum_out) csum_out[j] = csum;
    }
}

// ctx_bias[r] = dec_b[r] + dot(dec_Wih[r, H:2H], context)
__global__ __launch_bounds__(256)
void ctx_bias_k(const float* __restrict__ dec_Wih,
                const float* __restrict__ dec_b,
                const float* __restrict__ ctx,
                float* __restrict__ out)
{
    const int wv = threadIdx.x >> 6;
    const int lane = threadIdx.x & 63;
    const int r = blockIdx.x * 4 + wv;
    const float* wr = dec_Wih + (size_t)r * (2 * HDIM) + HDIM;
    float s = 0.f;
    for (int k = lane; k < HDIM; k += 64) s += wr[k] * ctx[k];
#pragma unroll
    for (int off = 32; off > 0; off >>= 1) s += __shfl_xor(s, off);
    if (lane == 0) out[r] = s + dec_b[r];
}

// ---------------------------------------------------------------------------
// dec_fused: decoder LSTM + ticket-queue logits GEMM with fused argmax.
// ---------------------------------------------------------------------------
__global__ __launch_bounds__(512, 1)
void dec_fused(const float* __restrict__ dec_Whh,
               const float* __restrict__ G_dec,
               const float* __restrict__ ctxb,
               const float* __restrict__ h_init,
               const float* __restrict__ c_init,
               float* __restrict__ dec_h,       // (S+1, H), 0xFF prefill
               const float* __restrict__ out_w,
               const float* __restrict__ out_b,
               float* __restrict__ out,
               int* __restrict__ ticket,        // zeroed
               int* __restrict__ cuslot,        // int[2048], zeroed
               unsigned long long* __restrict__ amax)  // u64[1024], zeroed
{
    __shared__ f4 hbuf[256];
    __shared__ float As[16][132];
    __shared__ float Bs[16][132];
    __shared__ int sh_flag;

    const int tid = threadIdx.x;
    const int bid = blockIdx.x;

    if (bid < 128) {
        // ------------------- decoder LSTM (CU-registered) -------------------
        if (tid == 0) agent_storei(&cuslot[cu_key()], 1);
        __builtin_amdgcn_s_setprio(1);

        const int g  = bid;
        const int wv = tid >> 6;
        const int lg = tid & 63;
        const int j  = g * 8 + wv;

        f4 W[4][4];
#pragma unroll
        for (int q = 0; q < 4; ++q)
#pragma unroll
            for (int i = 0; i < 4; ++i)
                W[q][i] = *(const f4*)(dec_Whh + (size_t)(j + q * HDIM) * HDIM
                                       + 4 * lg + 256 * i);

        float c = 0.0f;
        if (lg == 0) c = c_init[j];
        const float gctx = ctxb[(size_t)(lg & 3) * HDIM + j];
        float gnow = G_dec[(size_t)(lg & 3) * HDIM + j] + gctx;

        for (int t = 0; t < S_LEN; ++t) {
#pragma unroll
            for (int q = 0; q < 4; ++q)
#pragma unroll
                for (int i = 0; i < 4; ++i)
                    asm volatile("" : "+v"(W[q][i]));

            const float* hp = (t == 0) ? h_init
                                       : (dec_h + (size_t)(t - 1) * HDIM);
            if (wv == 0) {
                f4 a, b, cc, d;
                const float* p = hp + 4 * lg;
                for (;;) {
                    llc_load_4x4(p, a, b, cc, d);
                    if (!__any(any_nan16(a, b, cc, d))) break;
                    __builtin_amdgcn_s_sleep(1);
                }
                hbuf[swz(lg)]       = a;
                hbuf[swz(64 + lg)]  = b;
                hbuf[swz(128 + lg)] = cc;
                hbuf[swz(192 + lg)] = d;
            }
            __syncthreads();

            int tn = (t + 1 < S_LEN) ? (t + 1) : t;
            float gnext = G_dec[(size_t)tn * (4 * HDIM) + (lg & 3) * HDIM + j]
                          + gctx;

            f4 h0 = hbuf[swz(lg)];
            f4 h1 = hbuf[swz(64 + lg)];
            f4 h2 = hbuf[swz(128 + lg)];
            f4 h3 = hbuf[swz(192 + lg)];
            float p0 = 0.f, p1 = 0.f, p2 = 0.f, p3 = 0.f;
            f4 hv;
#pragma unroll
            for (int i = 0; i < 4; ++i) {
                hv = (i == 0) ? h0 : (i == 1) ? h1 : (i == 2) ? h2 : h3;
                p0 = fmaf(W[0][i].x, hv.x, fmaf(W[0][i].y, hv.y,
                     fmaf(W[0][i].z, hv.z, fmaf(W[0][i].w, hv.w, p0))));
                p1 = fmaf(W[1][i].x, hv.x, fmaf(W[1][i].y, hv.y,
                     fmaf(W[1][i].z, hv.z, fmaf(W[1][i].w, hv.w, p1))));
                p2 = fmaf(W[2][i].x, hv.x, fmaf(W[2][i].y, hv.y,
                     fmaf(W[2][i].z, hv.z, fmaf(W[2][i].w, hv.w, p2))));
                p3 = fmaf(W[3][i].x, hv.x, fmaf(W[3][i].y, hv.y,
                     fmaf(W[3][i].z, hv.z, fmaf(W[3][i].w, hv.w, p3))));
            }

            float t01 = __shfl_xor((lg & 1) ? p0 : p1, 1);
            float s01 = ((lg & 1) ? p1 : p0) + t01;
            float t23 = __shfl_xor((lg & 1) ? p2 : p3, 1);
            float s23 = ((lg & 1) ? p3 : p2) + t23;
            float tq  = __shfl_xor((lg & 2) ? s01 : s23, 2);
            float s   = ((lg & 2) ? s23 : s01) + tq;
            s += __shfl_xor(s, 4);
            s += __shfl_xor(s, 8);
            s += __shfl_xor(s, 16);
            s += __shfl_xor(s, 32);

            float pre = s + gnow;
            float act = ((lg & 3) == 2) ? tanhf(pre) : sigmoidf_(pre);
            float a1 = __shfl(act, 1);
            float a2 = __shfl(act, 2);
            float a3 = __shfl(act, 3);

            if (lg == 0) {
                c = a1 * c + act * a2;
                float h = a3 * tanhf(c);
                agent_storef(dec_h + (size_t)t * HDIM + j, h);
            }
            gnow = gnext;
            __syncthreads();
        }
        if (lg == 0)   // shadow completion row
            agent_storef(dec_h + (size_t)S_LEN * HDIM + j, 0.0f);
        __builtin_amdgcn_s_setprio(0);
        // fall through to the ticket loop (safety net + tail work)
    } else {
        // ----------------------- worker CU check -----------------------
        __builtin_amdgcn_s_sleep(127);
        __builtin_amdgcn_s_sleep(127);
        if (tid == 0) sh_flag = llc_loadi(&cuslot[cu_key()]);
        __syncthreads();
        if (sh_flag) return;        // on an LSTM CU: vacate
    }

    // ------------------- ticket-queue logits tiles -------------------
    for (;;) {
        if (tid == 0)
            sh_flag = __hip_atomic_fetch_add(ticket, 1, __ATOMIC_RELAXED,
                                             __HIP_MEMORY_SCOPE_AGENT);
        __syncthreads();
        const int tk = sh_flag;
        __syncthreads();
        if (tk >= NTICKETS) break;
        const int mt = tk / NTILE_N;
        const int nt = tk % NTILE_N;
        const int m0 = mt * 128;
        const int n0 = nt * 128;

        // progress certificate
        if (mt < 7) {
            if (tid == 0) {
                const float* p = dec_h + (size_t)(m0 + 128) * HDIM;
                float v = llc_loadf(p);
                while (v != v) { __builtin_amdgcn_s_sleep(32); v = llc_loadf(p); }
            }
        } else {
            if (tid < 64) {
                const float* p = dec_h + (size_t)S_LEN * HDIM + 4 * tid;
                f4 a, b, cc, d;
                for (;;) {
                    llc_load_4x4(p, a, b, cc, d);
                    if (!__any(any_nan16(a, b, cc, d))) break;
                    __builtin_amdgcn_s_sleep(32);
                }
            }
        }
        __syncthreads();

        float acc[8][4];
#pragma unroll
        for (int r = 0; r < 8; ++r)
#pragma unroll
            for (int cc = 0; cc < 4; ++cc) acc[r][cc] = 0.0f;

        const int ty = tid >> 5;
        const int tx = tid & 31;
        const int lm = tid >> 2;
        const int c4 = (tid & 3) * 4;

        for (int k0 = 0; k0 < HDIM; k0 += 16) {
            float4 v = *(const float4*)(dec_h + (size_t)(m0 + lm) * HDIM
                                        + k0 + c4);
            As[c4 + 0][lm] = v.x; As[c4 + 1][lm] = v.y;
            As[c4 + 2][lm] = v.z; As[c4 + 3][lm] = v.w;
            float4 w = *(const float4*)(out_w + (size_t)(n0 + lm) * HDIM
                                        + k0 + c4);
            Bs[c4 + 0][lm] = w.x; Bs[c4 + 1][lm] = w.y;
            Bs[c4 + 2][lm] = w.z; Bs[c4 + 3][lm] = w.w;
            __syncthreads();
#pragma unroll
            for (int k = 0; k < 16; ++k) {
                f4 a0 = *(const f4*)&As[k][ty * 8];
                f4 a1 = *(const f4*)&As[k][ty * 8 + 4];
                f4 b  = *(const f4*)&Bs[k][tx * 4];
                float av[8] = {a0.x,a0.y,a0.z,a0.w,a1.x,a1.y,a1.z,a1.w};
                float bv[4] = {b.x,b.y,b.z,b.w};
#pragma unroll
                for (int r = 0; r < 8; ++r)
#pragma unroll
                    for (int cc = 0; cc < 4; ++cc)
                        acc[r][cc] = fmaf(av[r], bv[cc], acc[r][cc]);
            }
            __syncthreads();
        }

        const int mbase = m0 + ty * 8;
        const int nbase = n0 + tx * 4;
#pragma unroll
        for (int r = 0; r < 8; ++r) {
            f4 o;
            o.x = acc[r][0] + out_b[nbase + 0];
            o.y = acc[r][1] + out_b[nbase + 1];
            o.z = acc[r][2] + out_b[nbase + 2];
            o.w = acc[r][3] + out_b[nbase + 3];
            *(f4*)(out + (size_t)(mbase + r) * VDIM + nbase) = o;

            // fused argmax: packed (monotonic-float, inverted-col) key
            unsigned long long best = 0ull;
#pragma unroll
            for (int cc = 0; cc < 4; ++cc) {
                float val = (cc == 0) ? o.x : (cc == 1) ? o.y
                           : (cc == 2) ? o.z : o.w;
                unsigned um = __float_as_uint(val);
                um = (um & 0x80000000u) ? ~um : (um | 0x80000000u);
                unsigned long long key = ((unsigned long long)um << 32)
                    | (unsigned long long)(0xFFFFFFFFu - (unsigned)(nbase + cc));
                if (key > best) best = key;
            }
#pragma unroll
            for (int off = 1; off < 32; off <<= 1) {
                unsigned long long other = __shfl_xor(best, off);
                if (other > best) best = other;
            }
            if (tx == 0)
                atomicMax(&amax[mbase + r], best);
        }
    }
}

// decode argmax keys -> float indices
__global__ __launch_bounds__(256)
void idx_final(const unsigned long long* __restrict__ amax,
               float* __restrict__ out_idx)
{
    int i = blockIdx.x * 256 + threadIdx.x;
    if (i < S_LEN) {
        unsigned col = 0xFFFFFFFFu - (unsigned)(amax[i] & 0xFFFFFFFFull);
        out_idx[i] = (float)col;
    }
}

extern "C" void kernel_launch(void* const* d_in, const int* in_sizes, int n_in,
                              void* d_out, int out_size, void* d_ws, size_t ws_size,
                              hipStream_t stream)
{
    (void)in_sizes; (void)n_in; (void)out_size; (void)ws_size;

    const int*   input_seq = (const int*)d_in[0];
    const int*   gold_seq  = (const int*)d_in[1];
    const float* embed     = (const float*)d_in[2];
    const float* enc_Wih   = (const float*)d_in[3];
    const float* enc_Whh   = (const float*)d_in[4];
    const float* enc_b     = (const float*)d_in[5];
    const float* dec_Wih   = (const float*)d_in[6];
    const float* dec_Whh   = (const float*)d_in[7];
    const float* dec_b     = (const float*)d_in[8];
    // d_in[9..14]: attention params — dead code
    const float* out_w     = (const float*)d_in[15];
    const float* out_b     = (const float*)d_in[16];

    float* out = (float*)d_out;
    float* G_enc = out;                   // head (dead before logits overwrite)
    float* G_dec = out + GDEC_OFF;        // tail (clobber-ordering proof above)

    // workspace (bytes): 0 ticket | 256 cuslot[2048]B? ints | 2560 amax u64[1024]
    //                  | 12288 zerovec | ... (floats below)
    char*  wsb     = (char*)d_ws;
    int*   ticket  = (int*)wsb;                         // 4 B
    int*   cuslot  = (int*)(wsb + 256);                 // 2048 ints = 8 KB
    unsigned long long* amax = (unsigned long long*)(wsb + 8448);  // 8 KB
    float* zerovec = (float*)(wsb + 16640);             // 1024 f
    float* c0      = zerovec + 1024;
    float* ctx     = c0 + 1024;
    float* ctxb    = ctx + 1024;                        // 4096 f
    float* enc_out = ctxb + 4096;                       // S*H
    float* dec_h   = enc_out + 1048576;                 // (S+1)*H

    // zero ctrl+zerovec region (ticket, cuslot, amax, zerovec): 16640+4096 B
    hipMemsetAsync(d_ws, 0, 20736, stream);
    hipMemsetAsync(enc_out, 0xFF, (size_t)S_LEN * HDIM * 4, stream);
    hipMemsetAsync(dec_h,   0xFF, (size_t)(S_LEN + 1) * HDIM * 4, stream);

    // both input GEMMs, one launch
    g_both<<<dim3(32, 16), 256, 0, stream>>>(
        embed, input_seq, gold_seq, enc_Wih, enc_b, dec_Wih, G_enc, G_dec);

    // encoder (round-5 proven)
    lstm_seq<<<128, 512, 0, stream>>>(
        enc_Whh, G_enc, zerovec, zerovec, enc_out, c0, ctx, S_LEN);

    // ctxb = dec_b + dec_Wih[:,H:] @ ctx
    ctx_bias_k<<<1024, 256, 0, stream>>>(dec_Wih, dec_b, ctx, ctxb);

    // decoder + logits + argmax, fused with CU-exclusion + ticket queue
    dec_fused<<<128 + NTICKETS, 512, 0, stream>>>(
        dec_Whh, G_dec, ctxb, enc_out + (size_t)(S_LEN - 1) * HDIM, c0,
        dec_h, out_w, out_b, out, ticket, cuslot, amax);

    // idxs -> d_out[S*V : S*V + S)
    idx_final<<<4, 256, 0, stream>>>(amax, out + (size_t)S_LEN * VDIM);
}